// Round 3
// baseline (12496.405 us; speedup 1.0000x reference)
//
#include <hip/hip_runtime.h>
#include <hip/hip_bf16.h>
#include <cstdint>
#include <cstddef>

typedef __hip_bfloat16 bf16;

#define NATOMS 8000
#define NEDGES 100000
#define NTRIP  500000
#define NGRAPH 64
#define HD     128
#define NRR    6
#define NSNR   42
#define NBB    8
#define NBLKS  6

__device__ __forceinline__ float siluf(float x){ return x / (1.f + __expf(-x)); }

__global__ void zerof_k(float* __restrict__ p, int n)
{
    int i = blockIdx.x * 256 + threadIdx.x;
    if (i < n) p[i] = 0.f;
}

// ---------------------------------------------------------------------------
// Tiled GEMM: out[M, ncols] = epi(A[M,K] @ B[K x ncols, row-stride ldb] + bias)
// epi: 0 = linear, 1 = silu, 2 = silu + res   (res ld = 128)
// Stores fp32 (outF) or bf16 (outB). Block 256 thr, tile 64 x 128, BK=16.
// ---------------------------------------------------------------------------
__global__ __launch_bounds__(256)
void gemm_k(const float* __restrict__ A, int M, int K,
            const float* __restrict__ B, int ldb,
            const float* __restrict__ bias,
            const float* __restrict__ res,
            float* __restrict__ outF, bf16* __restrict__ outB, int ldo, int epi)
{
    __shared__ float As[16][68];
    __shared__ float Bs[16][128];
    const int tid  = threadIdx.x;
    const int row0 = blockIdx.x * 64;
    const int col0 = blockIdx.y * 128;
    const int tx = tid & 31;
    const int ty = tid >> 5;

    float acc[8][4];
    #pragma unroll
    for (int r = 0; r < 8; ++r)
        #pragma unroll
        for (int c = 0; c < 4; ++c) acc[r][c] = 0.f;

    for (int k0 = 0; k0 < K; k0 += 16) {
        __syncthreads();
        #pragma unroll
        for (int it = 0; it < 4; ++it) {
            int idx = tid + 256 * it;
            int r = idx >> 4, kk = idx & 15;
            int grow = row0 + r;
            float v = 0.f;
            if (grow < M) v = A[(size_t)grow * K + k0 + kk];
            As[kk][r] = v;
        }
        #pragma unroll
        for (int it = 0; it < 8; ++it) {
            int idx = tid + 256 * it;
            int kk = idx >> 7, n = idx & 127;
            Bs[kk][n] = B[(size_t)(k0 + kk) * ldb + col0 + n];
        }
        __syncthreads();
        #pragma unroll
        for (int kk = 0; kk < 16; ++kk) {
            float4 a0 = *(const float4*)&As[kk][ty * 8];
            float4 a1 = *(const float4*)&As[kk][ty * 8 + 4];
            float a[8] = {a0.x, a0.y, a0.z, a0.w, a1.x, a1.y, a1.z, a1.w};
            float b[4];
            #pragma unroll
            for (int c = 0; c < 4; ++c) b[c] = Bs[kk][tx + 32 * c];
            #pragma unroll
            for (int r = 0; r < 8; ++r)
                #pragma unroll
                for (int c = 0; c < 4; ++c) acc[r][c] += a[r] * b[c];
        }
    }

    #pragma unroll
    for (int r = 0; r < 8; ++r) {
        int grow = row0 + ty * 8 + r;
        if (grow >= M) continue;
        #pragma unroll
        for (int c = 0; c < 4; ++c) {
            int n = tx + 32 * c;
            float t = acc[r][c];
            if (bias) t += bias[col0 + n];
            if (epi >= 1) t = siluf(t);
            if (epi == 2) t += res[(size_t)grow * 128 + col0 + n];
            size_t o = (size_t)grow * ldo + col0 + n;
            if (outB) outB[o] = __float2bfloat16(t);
            else      outF[o] = t;
        }
    }
}

// A0[a,h] = sum_l emb_table[a,l] * emb_w[l,h];  A1 same with emb_w rows 128..255
__global__ void emb_lin_k(const float* __restrict__ emb_table, const float* __restrict__ emb_w,
                          float* __restrict__ A0, float* __restrict__ A1)
{
    __shared__ float er[HD];
    int a = blockIdx.x, h = threadIdx.x;
    er[h] = emb_table[a * HD + h];
    __syncthreads();
    float acc0 = 0.f, acc1 = 0.f;
    #pragma unroll 8
    for (int l = 0; l < HD; ++l) {
        float e = er[l];
        acc0 += e * emb_w[l * HD + h];
        acc1 += e * emb_w[(HD + l) * HD + h];
    }
    A0[a * HD + h] = acc0;
    A1[a * HD + h] = acc1;
}

// rbf_h[e,h] = silu(rbf[e,:]@emb_rbf_w + emb_rbf_b)
__global__ void rbfh_k(const float* __restrict__ rbf, const float* __restrict__ W,
                       const float* __restrict__ bb, float* __restrict__ out)
{
    int idx = blockIdx.x * 256 + threadIdx.x;
    if (idx >= NEDGES * HD) return;
    int e = idx >> 7, h = idx & 127;
    float acc = bb[h];
    #pragma unroll
    for (int r = 0; r < NRR; ++r) acc += rbf[e * NRR + r] * W[r * HD + h];
    out[idx] = siluf(acc);
}

// x[e,h] = silu(lin3[e,h] + A0[z[i[e]],h] + A1[z[j[e]],h] + emb_b[h])
__global__ void emb_fin_k(const float* __restrict__ lin3, const int* __restrict__ z,
                          const int* __restrict__ ii, const int* __restrict__ jj,
                          const float* __restrict__ A0, const float* __restrict__ A1,
                          const float* __restrict__ emb_b, float* __restrict__ x)
{
    int idx = blockIdx.x * 256 + threadIdx.x;
    if (idx >= NEDGES * HD) return;
    int e = idx >> 7, h = idx & 127;
    int zi = z[ii[e]], zj = z[jj[e]];
    float t = lin3[idx] + A0[zi * HD + h] + A1[zj * HD + h] + emb_b[h];
    x[idx] = siluf(t);
}

// sbf_p[T,8] = sbf[T,42] @ W[42,8]
__global__ void sbf_proj_k(const float* __restrict__ sbf, const float* __restrict__ W,
                           float* __restrict__ sp)
{
    __shared__ float Ws[NSNR * NBB];
    for (int s = threadIdx.x; s < NSNR * NBB; s += 256) Ws[s] = W[s];
    __syncthreads();
    int t = blockIdx.x * 256 + threadIdx.x;
    if (t >= NTRIP) return;
    float acc[NBB];
    #pragma unroll
    for (int n = 0; n < NBB; ++n) acc[n] = 0.f;
    #pragma unroll
    for (int r = 0; r < NSNR; ++r) {
        float v = sbf[(size_t)t * NSNR + r];
        #pragma unroll
        for (int n = 0; n < NBB; ++n) acc[n] += v * Ws[r * NBB + n];
    }
    #pragma unroll
    for (int n = 0; n < NBB; ++n) sp[(size_t)t * NBB + n] = acc[n];
}

// x_kj[e,h] *= (rbf[e,:] @ W[6,128])[h]
__global__ void rbf_scale_k(float* __restrict__ x, const float* __restrict__ rbf,
                            const float* __restrict__ W)
{
    int idx = blockIdx.x * 256 + threadIdx.x;
    if (idx >= NEDGES * HD) return;
    int e = idx >> 7, h = idx & 127;
    float acc = 0.f;
    #pragma unroll
    for (int r = 0; r < NRR; ++r) acc += rbf[e * NRR + r] * W[r * HD + h];
    x[idx] *= acc;
}

// t_edge[e,h] = (rbf@out_rbf_w[k])[e,h] * x[e,h]
__global__ void out_scale_k(const float* __restrict__ x, const float* __restrict__ rbf,
                            const float* __restrict__ W, float* __restrict__ out)
{
    int idx = blockIdx.x * 256 + threadIdx.x;
    if (idx >= NEDGES * HD) return;
    int e = idx >> 7, h = idx & 127;
    float acc = 0.f;
    #pragma unroll
    for (int r = 0; r < NRR; ++r) acc += rbf[e * NRR + r] * W[r * HD + h];
    out[idx] = x[idx] * acc;
}

// Wt[l,j,i] = W[i,j,l]
__global__ void transposeW_k(const float* __restrict__ W, float* __restrict__ Wt)
{
    int idx = blockIdx.x * 256 + threadIdx.x;
    if (idx >= HD * NBB * HD) return;
    int l = idx >> 10;
    int r = idx & 1023;
    int j = r >> 7;
    int i = r & 127;
    Wt[idx] = W[i * (NBB * HD) + j * HD + l];
}

// pass over j-slice: m[idx_ji[t], h] += sum_{j<js} sp[t, jbase+j] * y[idx_kj[t], j*128+h]
__global__ __launch_bounds__(256)
void trip_scatter_k(const float* __restrict__ sp, const bf16* __restrict__ y,
                    const int* __restrict__ idx_kj, const int* __restrict__ idx_ji,
                    float* __restrict__ out, int jbase, int js)
{
    int t = blockIdx.x * 2 + (threadIdx.x >> 7);
    if (t >= NTRIP) return;
    int h = threadIdx.x & 127;
    int ekj = idx_kj[t], eji = idx_ji[t];
    const bf16* yr = y + (size_t)ekj * (js * HD) + h;
    const float* s = sp + (size_t)t * NBB + jbase;
    float acc = 0.f;
    for (int j = 0; j < js; ++j) acc += s[j] * __bfloat162float(yr[j * HD]);
    atomicAdd(&out[(size_t)eji * HD + h], acc);
}

// t_atom[i[e], h] += t_edge[e, h]
__global__ void edge_scatter_k(const float* __restrict__ te, const int* __restrict__ ii,
                               float* __restrict__ ta)
{
    int idx = blockIdx.x * 256 + threadIdx.x;
    if (idx >= NEDGES * HD) return;
    int e = idx >> 7, h = idx & 127;
    atomicAdd(&ta[(size_t)ii[e] * HD + h], te[idx]);
}

// P[a] += ta[a,:] . w[:]
__global__ void p_accum_k(const float* __restrict__ ta, const float* __restrict__ w,
                          float* __restrict__ P)
{
    int a = blockIdx.x;
    int l = threadIdx.x;
    float v = ta[(size_t)a * HD + l] * w[l] + ta[(size_t)a * HD + 64 + l] * w[64 + l];
    #pragma unroll
    for (int off = 32; off > 0; off >>= 1) v += __shfl_down(v, off);
    if (l == 0) P[a] += v;
}

__global__ void graph_sum_k(const float* __restrict__ P, const int* __restrict__ batch,
                            float* __restrict__ outg)
{
    int a = blockIdx.x * 256 + threadIdx.x;
    if (a >= NATOMS) return;
    atomicAdd(&outg[batch[a]], P[a]);
}

// ---------------------------------------------------------------------------
extern "C" void kernel_launch(void* const* d_in, const int* in_sizes, int n_in,
                              void* d_out, int out_size, void* d_ws, size_t ws_size,
                              hipStream_t stream)
{
    const int*   z         = (const int*)  d_in[0];
    const float* rbf       = (const float*)d_in[1];
    const float* sbf       = (const float*)d_in[2];
    const int*   ii        = (const int*)  d_in[3];
    const int*   jj        = (const int*)  d_in[4];
    const int*   idx_kj    = (const int*)  d_in[5];
    const int*   idx_ji    = (const int*)  d_in[6];
    const int*   batch     = (const int*)  d_in[7];
    const float* emb_table = (const float*)d_in[8];
    const float* emb_rbf_w = (const float*)d_in[9];
    const float* emb_rbf_b = (const float*)d_in[10];
    const float* emb_w     = (const float*)d_in[11];
    const float* emb_b     = (const float*)d_in[12];
    const float* int_rbf_w = (const float*)d_in[13];
    const float* int_sbf_w = (const float*)d_in[14];
    const float* int_kj_w  = (const float*)d_in[15];
    const float* int_kj_b  = (const float*)d_in[16];
    const float* int_ji_w  = (const float*)d_in[17];
    const float* int_ji_b  = (const float*)d_in[18];
    const float* int_W     = (const float*)d_in[19];
    const float* int_bef_w = (const float*)d_in[20];
    const float* int_bef_b = (const float*)d_in[21];
    const float* int_lin_w = (const float*)d_in[22];
    const float* int_lin_b = (const float*)d_in[23];
    const float* int_aft_w = (const float*)d_in[24];
    const float* int_aft_b = (const float*)d_in[25];
    const float* out_rbf_w = (const float*)d_in[26];
    const float* out_lins_w= (const float*)d_in[27];
    const float* out_lins_b= (const float*)d_in[28];
    const float* out_w     = (const float*)d_in[29];
    float* d_outf          = (float*)d_out;

    const size_t EH = (size_t)NEDGES * HD;

    // ---- workspace layout ----
    char* base = (char*)d_ws;
    float* bufA   = (float*)base;                 base += EH * 4;                 // x
    float* bufC   = (float*)base;                 base += EH * 4;                 // x_kj / tmp / t_edge
    float* bufD   = (float*)base;                 base += EH * 4;                 // x_ji + m
    float* sbfp   = (float*)base;                 base += (size_t)NTRIP * NBB * 4;
    float* t_atom = (float*)base;                 base += (size_t)NATOMS * HD * 4;
    float* t_atom2= (float*)base;                 base += (size_t)NATOMS * HD * 4;
    float* P_atom = (float*)base;                 base += (size_t)NATOMS * 4;
    float* A0     = (float*)base;                 base += 95 * HD * 4 + 128;
    float* A1     = (float*)base;                 base += 95 * HD * 4 + 128;
    float* Wt     = (float*)base;                 base += (size_t)HD * NBB * HD * 4;
    bf16*  ybuf   = (bf16*)base;
    size_t fixed  = (size_t)(base - (char*)d_ws);
    float* tmp    = bufC;  // alias: bufC dead when tmp is live

    // smallest j-split whose y-slice fits in remaining workspace (ws_size is
    // constant across calls -> deterministic, graph-safe)
    int nsplit = 8;
    for (int s = 1; s <= 8; s *= 2) {
        size_t yb = (size_t)NEDGES * (NBB / s) * HD * 2;
        if (fixed + yb <= ws_size) { nsplit = s; break; }
    }
    const int JS = NBB / nsplit;

    auto gemm = [&](const float* A, int M, int K, const float* B, int ldb,
                    const float* bias, const float* res,
                    float* oF, bf16* oB, int ldo, int epi, int ntile) {
        dim3 g((M + 63) / 64, ntile);
        gemm_k<<<g, 256, 0, stream>>>(A, M, K, B, ldb, bias, res, oF, oB, ldo, epi);
    };
    auto zero = [&](float* p, size_t n) {
        zerof_k<<<((int)n + 255) / 256, 256, 0, stream>>>(p, (int)n);
    };

    auto out_block = [&](const float* xe, int k) {
        zero(t_atom, (size_t)NATOMS * HD);
        out_scale_k<<<(NEDGES * HD + 255) / 256, 256, 0, stream>>>(
            xe, rbf, out_rbf_w + (size_t)k * NRR * HD, bufC);
        edge_scatter_k<<<(NEDGES * HD + 255) / 256, 256, 0, stream>>>(bufC, ii, t_atom);
        const float* lw = out_lins_w + (size_t)k * 3 * HD * HD;
        const float* lb = out_lins_b + (size_t)k * 3 * HD;
        gemm(t_atom,  NATOMS, HD, lw,               HD, lb,          nullptr, t_atom2, nullptr, HD, 1, 1);
        gemm(t_atom2, NATOMS, HD, lw + HD * HD,     HD, lb + HD,     nullptr, t_atom,  nullptr, HD, 1, 1);
        gemm(t_atom,  NATOMS, HD, lw + 2 * HD * HD, HD, lb + 2 * HD, nullptr, t_atom2, nullptr, HD, 1, 1);
        p_accum_k<<<NATOMS, 64, 0, stream>>>(t_atom2, out_w + (size_t)k * HD, P_atom);
    };

    // ---------------- Embedding block (no concat buffer) ----------------
    emb_lin_k<<<95, HD, 0, stream>>>(emb_table, emb_w, A0, A1);
    rbfh_k<<<(NEDGES * HD + 255) / 256, 256, 0, stream>>>(rbf, emb_rbf_w, emb_rbf_b, bufC);
    gemm(bufC, NEDGES, HD, emb_w + 2 * HD * HD, HD, nullptr, nullptr, bufD, nullptr, HD, 0, 1);
    emb_fin_k<<<(NEDGES * HD + 255) / 256, 256, 0, stream>>>(bufD, z, ii, jj, A0, A1, emb_b, bufA);

    zero(P_atom, NATOMS);
    out_block(bufA, 0);

    // ---------------- Interaction blocks ----------------
    for (int b = 0; b < NBLKS; ++b) {
        const float* kjw  = int_kj_w + (size_t)b * HD * HD;
        const float* jiw  = int_ji_w + (size_t)b * HD * HD;
        const float* befw = int_bef_w + (size_t)b * 2 * HD * HD;
        const float* befb = int_bef_b + (size_t)b * 2 * HD;
        const float* aftw = int_aft_w + (size_t)b * 4 * HD * HD;
        const float* aftb = int_aft_b + (size_t)b * 4 * HD;

        sbf_proj_k<<<(NTRIP + 255) / 256, 256, 0, stream>>>(
            sbf, int_sbf_w + (size_t)b * NSNR * NBB, sbfp);

        // x_kj = silu(x@Wkj+b) * rbf_p
        gemm(bufA, NEDGES, HD, kjw, HD, int_kj_b + (size_t)b * HD, nullptr, bufC, nullptr, HD, 1, 1);
        rbf_scale_k<<<(NEDGES * HD + 255) / 256, 256, 0, stream>>>(
            bufC, rbf, int_rbf_w + (size_t)b * NRR * HD);

        transposeW_k<<<(HD * NBB * HD + 255) / 256, 256, 0, stream>>>(
            int_W + (size_t)b * HD * NBB * HD, Wt);

        // x_ji first (bufD is the scatter target)
        gemm(bufA, NEDGES, HD, jiw, HD, int_ji_b + (size_t)b * HD, nullptr, bufD, nullptr, HD, 1, 1);

        // y slices + triplet scatter
        for (int p = 0; p < nsplit; ++p) {
            gemm(bufC, NEDGES, HD, Wt + p * JS * HD, NBB * HD, nullptr, nullptr,
                 nullptr, ybuf, JS * HD, 0, JS);
            trip_scatter_k<<<(NTRIP + 1) / 2, 256, 0, stream>>>(
                sbfp, ybuf, idx_kj, idx_ji, bufD, p * JS, JS);
        }

        // residual-before
        gemm(bufD, NEDGES, HD, befw, HD, befb, nullptr, tmp, nullptr, HD, 1, 1);
        gemm(tmp, NEDGES, HD, befw + HD * HD, HD, befb + HD, bufD, bufD, nullptr, HD, 2, 1);

        // h = silu(h@lin+b) + x
        gemm(bufD, NEDGES, HD, int_lin_w + (size_t)b * HD * HD, HD,
             int_lin_b + (size_t)b * HD, bufA, bufA, nullptr, HD, 2, 1);

        // residual-after x2
        for (int r = 0; r < 2; ++r) {
            gemm(bufA, NEDGES, HD, aftw + (size_t)(2 * r) * HD * HD, HD,
                 aftb + (size_t)(2 * r) * HD, nullptr, tmp, nullptr, HD, 1, 1);
            gemm(tmp, NEDGES, HD, aftw + (size_t)(2 * r + 1) * HD * HD, HD,
                 aftb + (size_t)(2 * r + 1) * HD, bufA, bufA, nullptr, HD, 2, 1);
        }

        out_block(bufA, b + 1);
    }

    // ---------------- Final graph reduction (into d_out directly) ----------------
    zero(d_outf, NGRAPH);
    graph_sum_k<<<(NATOMS + 255) / 256, 256, 0, stream>>>(P_atom, batch, d_outf);
}

// Round 4
// 10161.616 us; speedup vs baseline: 1.2298x; 1.2298x over previous
//
#include <hip/hip_runtime.h>
#include <cstdint>
#include <cstddef>

typedef unsigned short ushort_t;
typedef unsigned int uint_t;

#define NATOMS 8000
#define NEDGES 100000
#define NTRIP  500000
#define NGRAPH 64
#define HD     128
#define NRR    6
#define NSNR   42
#define NBB    8
#define NBLKS  6

using short8  = __attribute__((ext_vector_type(8))) short;
using floatx4 = __attribute__((ext_vector_type(4))) float;

__device__ __forceinline__ float siluf(float x){ return x / (1.f + __expf(-x)); }

// fp32 -> bf16 (RNE) as raw ushort
__device__ __forceinline__ ushort_t f2us(float f){
    uint_t u = __builtin_bit_cast(uint_t, f);
    u = (u + 0x7FFFu + ((u >> 16) & 1u)) >> 16;
    return (ushort_t)u;
}
__device__ __forceinline__ float us2f(ushort_t s){
    uint_t u = ((uint_t)s) << 16;
    return __builtin_bit_cast(float, u);
}

__global__ void zerof_k(float* __restrict__ p, int n)
{
    int i = blockIdx.x * 256 + threadIdx.x;
    if (i < n) p[i] = 0.f;
}

// ---------------------------------------------------------------------------
// Weight prep: fp32 [nmat][128][128] (k-major) -> bf16 ushort [nmat][128][128]
// transposed per matrix: dst[m][n][k] = src[m][k][n]
// ---------------------------------------------------------------------------
__global__ __launch_bounds__(256)
void transp128_k(const float* __restrict__ src, ushort_t* __restrict__ dst)
{
    __shared__ ushort_t L[128][130];
    int m = blockIdx.x;
    const float* S = src + (size_t)m * 16384;
    ushort_t* D = dst + (size_t)m * 16384;
    int tid = threadIdx.x;
    #pragma unroll
    for (int p = 0; p < 64; ++p) {
        int idx = p * 256 + tid;
        int k = idx >> 7, n = idx & 127;
        L[k][n] = f2us(S[idx]);
    }
    __syncthreads();
    #pragma unroll
    for (int p = 0; p < 64; ++p) {
        int idx = p * 256 + tid;       // idx = n*128 + k
        int n = idx >> 7, k = idx & 127;
        D[idx] = L[k][n];
    }
}

// int_W prep: src fp32 [6][128(i)][8(j)][128(l)] -> dst ushort [6][1024(j,i)][128(l)]
__global__ void transpWY_k(const float* __restrict__ src, ushort_t* __restrict__ dst)
{
    int rw = blockIdx.x * 256 + threadIdx.x;
    if (rw >= NBLKS * 1024) return;
    int m = rw >> 10, ji = rw & 1023, j = ji >> 7, i = ji & 127;
    const float* S = src + ((size_t)(m * 128 + i) * 8 + j) * 128;
    ushort_t* D = dst + (size_t)rw * 128;
    #pragma unroll 4
    for (int l = 0; l < 128; ++l) D[l] = f2us(S[l]);
}

// ---------------------------------------------------------------------------
// MFMA GEMM: out[M, gridDim.y*128] = epi(A[M,128] @ B) with B given pre-
// transposed bf16: Bt[n][k] (row stride 128). epi: 0 linear, 1 silu,
// 2 silu+res. Tile 128x128, BK=64, 4 waves (2x2), 16x16x32 bf16 MFMA.
// ---------------------------------------------------------------------------
__global__ __launch_bounds__(256)
void mgemm_k(const float* __restrict__ A, int M,
             const ushort_t* __restrict__ Bt,
             const float* __restrict__ bias,
             const float* __restrict__ res,
             float* __restrict__ outF, ushort_t* __restrict__ outB,
             int ldo, int epi)
{
    __shared__ ushort_t Al[128][72];   // row stride 144 B (16B-aligned)
    __shared__ ushort_t Bl[128][72];
    const int tid  = threadIdx.x;
    const int row0 = blockIdx.x * 128;
    const int col0 = blockIdx.y * 128;
    const int wave = tid >> 6, lane = tid & 63;
    const int wr = wave >> 1, wc = wave & 1;   // 2x2 wave grid, each 64x64
    const int lhi = lane >> 4, llo = lane & 15;

    floatx4 acc[4][4];
    #pragma unroll
    for (int a = 0; a < 4; ++a)
        #pragma unroll
        for (int b = 0; b < 4; ++b)
            #pragma unroll
            for (int q = 0; q < 4; ++q) acc[a][b][q] = 0.f;

    #pragma unroll
    for (int kh = 0; kh < 2; ++kh) {
        const int k0 = kh * 64;
        if (kh) __syncthreads();
        // stage A: 128 rows x 64 k, fp32 -> bf16
        #pragma unroll
        for (int p = 0; p < 8; ++p) {
            int idx = p * 256 + tid;          // 0..2047
            int r = idx >> 4, c4 = idx & 15;  // float4 col
            int grow = row0 + r;
            float4 v = make_float4(0.f, 0.f, 0.f, 0.f);
            if (grow < M) v = *(const float4*)(A + (size_t)grow * 128 + k0 + c4 * 4);
            ushort_t u0 = f2us(v.x), u1 = f2us(v.y), u2 = f2us(v.z), u3 = f2us(v.w);
            ushort4 pk; pk.x = u0; pk.y = u1; pk.z = u2; pk.w = u3;
            *(ushort4*)&Al[r][c4 * 4] = pk;
        }
        // stage B (already bf16, [n][k] row-major, stride 128)
        #pragma unroll
        for (int p = 0; p < 8; ++p) {
            int idx = p * 256 + tid;
            int n = idx >> 4, c4 = idx & 15;
            ushort4 v = *(const ushort4*)(Bt + (size_t)(col0 + n) * 128 + k0 + c4 * 4);
            *(ushort4*)&Bl[n][c4 * 4] = v;
        }
        __syncthreads();
        #pragma unroll
        for (int ks = 0; ks < 2; ++ks) {
            const int kk = ks * 32 + lhi * 8;
            short8 af[4], bf[4];
            #pragma unroll
            for (int tm = 0; tm < 4; ++tm)
                af[tm] = *(const short8*)&Al[wr * 64 + tm * 16 + llo][kk];
            #pragma unroll
            for (int tn = 0; tn < 4; ++tn)
                bf[tn] = *(const short8*)&Bl[wc * 64 + tn * 16 + llo][kk];
            #pragma unroll
            for (int tm = 0; tm < 4; ++tm)
                #pragma unroll
                for (int tn = 0; tn < 4; ++tn)
                    acc[tm][tn] = __builtin_amdgcn_mfma_f32_16x16x32_bf16(
                        af[tm], bf[tn], acc[tm][tn], 0, 0, 0);
        }
    }

    // epilogue: C[row][col], col = lane&15, row = (lane>>4)*4 + reg
    #pragma unroll
    for (int tm = 0; tm < 4; ++tm) {
        #pragma unroll
        for (int tn = 0; tn < 4; ++tn) {
            int coll = wc * 64 + tn * 16 + llo;
            int gcol = col0 + coll;
            #pragma unroll
            for (int q = 0; q < 4; ++q) {
                int growl = wr * 64 + tm * 16 + lhi * 4 + q;
                int grow = row0 + growl;
                if (grow >= M) continue;
                float t = acc[tm][tn][q];
                if (bias) t += bias[gcol];
                if (epi >= 1) t = siluf(t);
                if (epi == 2) t += res[(size_t)grow * 128 + coll];
                size_t o = (size_t)grow * ldo + gcol;
                if (outB) outB[o] = f2us(t);
                else      outF[o] = t;
            }
        }
    }
}

// ---------------------------------------------------------------------------
// Small kernels
// ---------------------------------------------------------------------------
__global__ void emb_lin_k(const float* __restrict__ emb_table, const float* __restrict__ emb_w,
                          float* __restrict__ A0, float* __restrict__ A1)
{
    __shared__ float er[HD];
    int a = blockIdx.x, h = threadIdx.x;
    er[h] = emb_table[a * HD + h];
    __syncthreads();
    float acc0 = 0.f, acc1 = 0.f;
    #pragma unroll 8
    for (int l = 0; l < HD; ++l) {
        float e = er[l];
        acc0 += e * emb_w[l * HD + h];
        acc1 += e * emb_w[(HD + l) * HD + h];
    }
    A0[a * HD + h] = acc0;
    A1[a * HD + h] = acc1;
}

__global__ void rbfh_k(const float* __restrict__ rbf, const float* __restrict__ W,
                       const float* __restrict__ bb, float* __restrict__ out)
{
    int idx = blockIdx.x * 256 + threadIdx.x;
    if (idx >= NEDGES * HD) return;
    int e = idx >> 7, h = idx & 127;
    float acc = bb[h];
    #pragma unroll
    for (int r = 0; r < NRR; ++r) acc += rbf[e * NRR + r] * W[r * HD + h];
    out[idx] = siluf(acc);
}

__global__ void emb_fin_k(const float* __restrict__ lin3, const int* __restrict__ z,
                          const int* __restrict__ ii, const int* __restrict__ jj,
                          const float* __restrict__ A0, const float* __restrict__ A1,
                          const float* __restrict__ emb_b, float* __restrict__ x)
{
    int idx = blockIdx.x * 256 + threadIdx.x;
    if (idx >= NEDGES * HD) return;
    int e = idx >> 7, h = idx & 127;
    int zi = z[ii[e]], zj = z[jj[e]];
    float t = lin3[idx] + A0[zi * HD + h] + A1[zj * HD + h] + emb_b[h];
    x[idx] = siluf(t);
}

__global__ void sbf_proj_k(const float* __restrict__ sbf, const float* __restrict__ W,
                           float* __restrict__ sp)
{
    __shared__ float Ws[NSNR * NBB];
    for (int s = threadIdx.x; s < NSNR * NBB; s += 256) Ws[s] = W[s];
    __syncthreads();
    int t = blockIdx.x * 256 + threadIdx.x;
    if (t >= NTRIP) return;
    float acc[NBB];
    #pragma unroll
    for (int n = 0; n < NBB; ++n) acc[n] = 0.f;
    #pragma unroll
    for (int r = 0; r < NSNR; ++r) {
        float v = sbf[(size_t)t * NSNR + r];
        #pragma unroll
        for (int n = 0; n < NBB; ++n) acc[n] += v * Ws[r * NBB + n];
    }
    #pragma unroll
    for (int n = 0; n < NBB; ++n) sp[(size_t)t * NBB + n] = acc[n];
}

__global__ void rbf_scale_k(float* __restrict__ x, const float* __restrict__ rbf,
                            const float* __restrict__ W)
{
    int idx = blockIdx.x * 256 + threadIdx.x;
    if (idx >= NEDGES * HD) return;
    int e = idx >> 7, h = idx & 127;
    float acc = 0.f;
    #pragma unroll
    for (int r = 0; r < NRR; ++r) acc += rbf[e * NRR + r] * W[r * HD + h];
    x[idx] *= acc;
}

// fused out_scale + edge->atom scatter
__global__ void out_scatter_k(const float* __restrict__ x, const float* __restrict__ rbf,
                              const float* __restrict__ W, const int* __restrict__ ii,
                              float* __restrict__ ta)
{
    int idx = blockIdx.x * 256 + threadIdx.x;
    if (idx >= NEDGES * HD) return;
    int e = idx >> 7, h = idx & 127;
    float acc = 0.f;
    #pragma unroll
    for (int r = 0; r < NRR; ++r) acc += rbf[e * NRR + r] * W[r * HD + h];
    atomicAdd(&ta[(size_t)ii[e] * HD + h], x[idx] * acc);
}

__global__ __launch_bounds__(256)
void trip_scatter_k(const float* __restrict__ sp, const ushort_t* __restrict__ y,
                    const int* __restrict__ idx_kj, const int* __restrict__ idx_ji,
                    float* __restrict__ out, int jbase, int js)
{
    int t = blockIdx.x * 2 + (threadIdx.x >> 7);
    if (t >= NTRIP) return;
    int h = threadIdx.x & 127;
    int ekj = idx_kj[t], eji = idx_ji[t];
    const ushort_t* yr = y + (size_t)ekj * (js * HD) + h;
    const float* s = sp + (size_t)t * NBB + jbase;
    float acc = 0.f;
    for (int j = 0; j < js; ++j) acc += s[j] * us2f(yr[j * HD]);
    atomicAdd(&out[(size_t)eji * HD + h], acc);
}

__global__ void p_accum_k(const float* __restrict__ ta, const float* __restrict__ w,
                          float* __restrict__ P)
{
    int a = blockIdx.x;
    int l = threadIdx.x;
    float v = ta[(size_t)a * HD + l] * w[l] + ta[(size_t)a * HD + 64 + l] * w[64 + l];
    #pragma unroll
    for (int off = 32; off > 0; off >>= 1) v += __shfl_down(v, off);
    if (l == 0) P[a] += v;
}

__global__ void graph_sum_k(const float* __restrict__ P, const int* __restrict__ batch,
                            float* __restrict__ outg)
{
    int a = blockIdx.x * 256 + threadIdx.x;
    if (a >= NATOMS) return;
    atomicAdd(&outg[batch[a]], P[a]);
}

// ---------------------------------------------------------------------------
extern "C" void kernel_launch(void* const* d_in, const int* in_sizes, int n_in,
                              void* d_out, int out_size, void* d_ws, size_t ws_size,
                              hipStream_t stream)
{
    const int*   z         = (const int*)  d_in[0];
    const float* rbf       = (const float*)d_in[1];
    const float* sbf       = (const float*)d_in[2];
    const int*   ii        = (const int*)  d_in[3];
    const int*   jj        = (const int*)  d_in[4];
    const int*   idx_kj    = (const int*)  d_in[5];
    const int*   idx_ji    = (const int*)  d_in[6];
    const int*   batch     = (const int*)  d_in[7];
    const float* emb_table = (const float*)d_in[8];
    const float* emb_rbf_w = (const float*)d_in[9];
    const float* emb_rbf_b = (const float*)d_in[10];
    const float* emb_w     = (const float*)d_in[11];
    const float* emb_b     = (const float*)d_in[12];
    const float* int_rbf_w = (const float*)d_in[13];
    const float* int_sbf_w = (const float*)d_in[14];
    const float* int_kj_w  = (const float*)d_in[15];
    const float* int_kj_b  = (const float*)d_in[16];
    const float* int_ji_w  = (const float*)d_in[17];
    const float* int_ji_b  = (const float*)d_in[18];
    const float* int_W     = (const float*)d_in[19];
    const float* int_bef_w = (const float*)d_in[20];
    const float* int_bef_b = (const float*)d_in[21];
    const float* int_lin_w = (const float*)d_in[22];
    const float* int_lin_b = (const float*)d_in[23];
    const float* int_aft_w = (const float*)d_in[24];
    const float* int_aft_b = (const float*)d_in[25];
    const float* out_rbf_w = (const float*)d_in[26];
    const float* out_lins_w= (const float*)d_in[27];
    const float* out_lins_b= (const float*)d_in[28];
    const float* out_w     = (const float*)d_in[29];
    float* d_outf          = (float*)d_out;

    const size_t EH = (size_t)NEDGES * HD;
    const size_t MSZ = 16384;   // 128*128

    // bf16 weight slot offsets (units of 16384)
    const int OFF_EMB = 0, OFF_KJ = 1, OFF_JI = 7, OFF_BEF = 13,
              OFF_LIN = 25, OFF_AFT = 31, OFF_OUTL = 55;  // total 76

    // ---- workspace layout ----
    char* base = (char*)d_ws;
    float* bufA   = (float*)base;                 base += EH * 4;                 // x
    float* bufC   = (float*)base;                 base += EH * 4;                 // x_kj / tmp
    float* bufD   = (float*)base;                 base += EH * 4;                 // x_ji + m
    float* sbfp   = (float*)base;                 base += (size_t)NTRIP * NBB * 4;
    float* t_atom = (float*)base;                 base += (size_t)NATOMS * HD * 4;
    float* t_atom2= (float*)base;                 base += (size_t)NATOMS * HD * 4;
    float* P_atom = (float*)base;                 base += (size_t)NATOMS * 4;
    float* A0     = (float*)base;                 base += 95 * HD * 4 + 128;
    float* A1     = (float*)base;                 base += 95 * HD * 4 + 128;
    ushort_t* w128= (ushort_t*)base;              base += 76 * MSZ * 2;
    ushort_t* wY  = (ushort_t*)base;              base += (size_t)NBLKS * 1024 * 128 * 2;
    ushort_t* ybuf= (ushort_t*)base;
    size_t fixed  = (size_t)(base - (char*)d_ws);
    float* tmp    = bufC;  // alias: bufC dead when tmp is live

    int nsplit = 8;
    for (int s = 1; s <= 8; s *= 2) {
        size_t yb = (size_t)NEDGES * (NBB / s) * HD * 2;
        if (fixed + yb <= ws_size) { nsplit = s; break; }
    }
    const int JS = NBB / nsplit;

    auto gemm = [&](const float* A, int M, const ushort_t* Bt,
                    const float* bias, const float* res,
                    float* oF, ushort_t* oB, int ldo, int epi, int ntile) {
        dim3 g((M + 127) / 128, ntile);
        mgemm_k<<<g, 256, 0, stream>>>(A, M, Bt, bias, res, oF, oB, ldo, epi);
    };
    auto zero = [&](float* p, size_t n) {
        zerof_k<<<((int)n + 255) / 256, 256, 0, stream>>>(p, (int)n);
    };

    // ---------------- weight prep (once per launch) ----------------
    transp128_k<<< 1, 256, 0, stream>>>(emb_w + 2 * MSZ, w128 + OFF_EMB * MSZ);
    transp128_k<<< 6, 256, 0, stream>>>(int_kj_w,   w128 + OFF_KJ  * MSZ);
    transp128_k<<< 6, 256, 0, stream>>>(int_ji_w,   w128 + OFF_JI  * MSZ);
    transp128_k<<<12, 256, 0, stream>>>(int_bef_w,  w128 + OFF_BEF * MSZ);
    transp128_k<<< 6, 256, 0, stream>>>(int_lin_w,  w128 + OFF_LIN * MSZ);
    transp128_k<<<24, 256, 0, stream>>>(int_aft_w,  w128 + OFF_AFT * MSZ);
    transp128_k<<<21, 256, 0, stream>>>(out_lins_w, w128 + OFF_OUTL* MSZ);
    transpWY_k<<<(NBLKS * 1024 + 255) / 256, 256, 0, stream>>>(int_W, wY);

    auto out_block = [&](const float* xe, int k) {
        zero(t_atom, (size_t)NATOMS * HD);
        out_scatter_k<<<(NEDGES * HD + 255) / 256, 256, 0, stream>>>(
            xe, rbf, out_rbf_w + (size_t)k * NRR * HD, ii, t_atom);
        const ushort_t* lw = w128 + (size_t)(OFF_OUTL + 3 * k) * MSZ;
        const float* lb = out_lins_b + (size_t)k * 3 * HD;
        gemm(t_atom,  NATOMS, lw,           lb,          nullptr, t_atom2, nullptr, HD, 1, 1);
        gemm(t_atom2, NATOMS, lw + MSZ,     lb + HD,     nullptr, t_atom,  nullptr, HD, 1, 1);
        gemm(t_atom,  NATOMS, lw + 2 * MSZ, lb + 2 * HD, nullptr, t_atom2, nullptr, HD, 1, 1);
        p_accum_k<<<NATOMS, 64, 0, stream>>>(t_atom2, out_w + (size_t)k * HD, P_atom);
    };

    // ---------------- Embedding block ----------------
    emb_lin_k<<<95, HD, 0, stream>>>(emb_table, emb_w, A0, A1);
    rbfh_k<<<(NEDGES * HD + 255) / 256, 256, 0, stream>>>(rbf, emb_rbf_w, emb_rbf_b, bufC);
    gemm(bufC, NEDGES, w128 + OFF_EMB * MSZ, nullptr, nullptr, bufD, nullptr, HD, 0, 1);
    emb_fin_k<<<(NEDGES * HD + 255) / 256, 256, 0, stream>>>(bufD, z, ii, jj, A0, A1, emb_b, bufA);

    zero(P_atom, NATOMS);
    out_block(bufA, 0);

    // ---------------- Interaction blocks ----------------
    for (int b = 0; b < NBLKS; ++b) {
        sbf_proj_k<<<(NTRIP + 255) / 256, 256, 0, stream>>>(
            sbf, int_sbf_w + (size_t)b * NSNR * NBB, sbfp);

        // x_kj = silu(x@Wkj+b) * rbf_p
        gemm(bufA, NEDGES, w128 + (size_t)(OFF_KJ + b) * MSZ,
             int_kj_b + (size_t)b * HD, nullptr, bufC, nullptr, HD, 1, 1);
        rbf_scale_k<<<(NEDGES * HD + 255) / 256, 256, 0, stream>>>(
            bufC, rbf, int_rbf_w + (size_t)b * NRR * HD);

        // x_ji (scatter target)
        gemm(bufA, NEDGES, w128 + (size_t)(OFF_JI + b) * MSZ,
             int_ji_b + (size_t)b * HD, nullptr, bufD, nullptr, HD, 1, 1);

        // y slices + triplet scatter
        for (int p = 0; p < nsplit; ++p) {
            gemm(bufC, NEDGES, wY + ((size_t)b * 1024 + (size_t)p * JS * 128) * 128,
                 nullptr, nullptr, nullptr, ybuf, JS * HD, 0, JS);
            trip_scatter_k<<<(NTRIP + 1) / 2, 256, 0, stream>>>(
                sbfp, ybuf, idx_kj, idx_ji, bufD, p * JS, JS);
        }

        // residual-before
        const ushort_t* bw = w128 + (size_t)(OFF_BEF + 2 * b) * MSZ;
        const float* bb = int_bef_b + (size_t)b * 2 * HD;
        gemm(bufD, NEDGES, bw,       bb,      nullptr, tmp,  nullptr, HD, 1, 1);
        gemm(tmp,  NEDGES, bw + MSZ, bb + HD, bufD,    bufD, nullptr, HD, 2, 1);

        // h = silu(h@lin+b) + x
        gemm(bufD, NEDGES, w128 + (size_t)(OFF_LIN + b) * MSZ,
             int_lin_b + (size_t)b * HD, bufA, bufA, nullptr, HD, 2, 1);

        // residual-after x2
        const ushort_t* aw = w128 + (size_t)(OFF_AFT + 4 * b) * MSZ;
        const float* ab = int_aft_b + (size_t)b * 4 * HD;
        for (int r = 0; r < 2; ++r) {
            gemm(bufA, NEDGES, aw + (size_t)(2 * r) * MSZ,
                 ab + (size_t)(2 * r) * HD, nullptr, tmp, nullptr, HD, 1, 1);
            gemm(tmp,  NEDGES, aw + (size_t)(2 * r + 1) * MSZ,
                 ab + (size_t)(2 * r + 1) * HD, bufA, bufA, nullptr, HD, 2, 1);
        }

        out_block(bufA, b + 1);
    }

    // ---------------- Final graph reduction ----------------
    zero(d_outf, NGRAPH);
    graph_sum_k<<<(NATOMS + 255) / 256, 256, 0, stream>>>(P_atom, batch, d_outf);
}

// Round 5
// 8774.347 us; speedup vs baseline: 1.4242x; 1.1581x over previous
//
#include <hip/hip_runtime.h>
#include <cstdint>
#include <cstddef>

typedef unsigned short ushort_t;
typedef unsigned int uint_t;

#define NATOMS 8000
#define NEDGES 100000
#define NTRIP  500000
#define NGRAPH 64
#define HD     128
#define NRR    6
#define NSNR   42
#define NBB    8
#define NBLKS  6
#define MSZ    16384

using short8   = __attribute__((ext_vector_type(8))) short;
using ushort8v = __attribute__((ext_vector_type(8))) unsigned short;
using floatx4  = __attribute__((ext_vector_type(4))) float;

__device__ __forceinline__ float siluf(float x){ return x / (1.f + __expf(-x)); }
__device__ __forceinline__ ushort_t f2us(float f){
    uint_t u = __builtin_bit_cast(uint_t, f);
    u = (u + 0x7FFFu + ((u >> 16) & 1u)) >> 16;
    return (ushort_t)u;
}
__device__ __forceinline__ float us2f(ushort_t s){
    uint_t u = ((uint_t)s) << 16;
    return __builtin_bit_cast(float, u);
}

__global__ void zerof_k(float* __restrict__ p, int n){ int i=blockIdx.x*256+threadIdx.x; if(i<n) p[i]=0.f; }
__global__ void zeroi_k(int* __restrict__ p, int n){ int i=blockIdx.x*256+threadIdx.x; if(i<n) p[i]=0; }

// ---------------- weight prep ----------------
__global__ __launch_bounds__(256)
void transp128_k(const float* __restrict__ src, ushort_t* __restrict__ dst)
{
    __shared__ ushort_t L[128][130];
    int m = blockIdx.x;
    const float* S = src + (size_t)m * MSZ;
    ushort_t* D = dst + (size_t)m * MSZ;
    int tid = threadIdx.x;
    #pragma unroll
    for (int p = 0; p < 64; ++p) {
        int idx = p * 256 + tid;
        int k = idx >> 7, n = idx & 127;
        L[k][n] = f2us(S[idx]);
    }
    __syncthreads();
    #pragma unroll
    for (int p = 0; p < 64; ++p) {
        int idx = p * 256 + tid;
        int n = idx >> 7, k = idx & 127;
        D[idx] = L[k][n];
    }
}

__global__ void transpWY_k(const float* __restrict__ src, ushort_t* __restrict__ dst)
{
    int rw = blockIdx.x * 256 + threadIdx.x;
    if (rw >= NBLKS * 1024) return;
    int m = rw >> 10, ji = rw & 1023, j = ji >> 7, i = ji & 127;
    const float* S = src + ((size_t)(m * 128 + i) * 8 + j) * 128;
    ushort_t* D = dst + (size_t)rw * 128;
    #pragma unroll 4
    for (int l = 0; l < 128; ++l) D[l] = f2us(S[l]);
}

// pack chain biases: [b][7][128] = bef0,bef1,lin,aft0..3
__global__ void pack_bc_k(const float* __restrict__ bef, const float* __restrict__ lin,
                          const float* __restrict__ aft, float* __restrict__ bc)
{
    int b = blockIdx.x;
    for (int i = threadIdx.x; i < 7 * HD; i += 256) {
        int s = i >> 7, h = i & 127;
        float v;
        if (s < 2)      v = bef[(size_t)(b * 2 + s) * HD + h];
        else if (s == 2) v = lin[(size_t)b * HD + h];
        else             v = aft[(size_t)(b * 4 + (s - 3)) * HD + h];
        bc[(size_t)b * 7 * HD + i] = v;
    }
}

// ---------------- CSR build ----------------
__global__ void hist_k(const int* __restrict__ idx, int n, int* __restrict__ cnt)
{
    int i = blockIdx.x * 256 + threadIdx.x;
    if (i < n) atomicAdd(&cnt[idx[i]], 1);
}
__global__ void blksum_k(const int* __restrict__ c, int n, int* __restrict__ bs)
{
    int i = blockIdx.x * 256 + threadIdx.x;
    int v = (i < n) ? c[i] : 0;
    #pragma unroll
    for (int off = 32; off; off >>= 1) v += __shfl_down(v, off);
    __shared__ int sh[4];
    if ((threadIdx.x & 63) == 0) sh[threadIdx.x >> 6] = v;
    __syncthreads();
    if (threadIdx.x == 0) bs[blockIdx.x] = sh[0] + sh[1] + sh[2] + sh[3];
}
__global__ void scanb_k(int* __restrict__ bs, int nb)   // single block, 1024 thr
{
    __shared__ int sh[1024];
    int t = threadIdx.x;
    int v = (t < nb) ? bs[t] : 0;
    sh[t] = v; __syncthreads();
    for (int off = 1; off < 1024; off <<= 1) {
        int u = (t >= off) ? sh[t - off] : 0;
        __syncthreads();
        sh[t] += u;
        __syncthreads();
    }
    if (t < nb) bs[t] = sh[t] - v;   // exclusive
}
__global__ void scanfin_k(const int* __restrict__ c, int n, const int* __restrict__ bs,
                          int* __restrict__ offs)
{
    __shared__ int sh[256];
    int t = threadIdx.x;
    int i = blockIdx.x * 256 + t;
    int v = (i < n) ? c[i] : 0;
    sh[t] = v; __syncthreads();
    for (int off = 1; off < 256; off <<= 1) {
        int u = (t >= off) ? sh[t - off] : 0;
        __syncthreads();
        sh[t] += u;
        __syncthreads();
    }
    if (i < n)  offs[i] = bs[blockIdx.x] + sh[t] - v;
    if (i == n - 1) offs[n] = bs[blockIdx.x] + sh[t];
}
__global__ void fill_k(const int* __restrict__ idx, int n, const int* __restrict__ offs,
                       int* __restrict__ cur, int* __restrict__ sorted)
{
    int i = blockIdx.x * 256 + threadIdx.x;
    if (i >= n) return;
    int e = idx[i];
    int p = offs[e] + atomicAdd(&cur[e], 1);
    sorted[p] = i;
}

// ---------------------------------------------------------------------------
// mgemm (round-4, validated): single-weight GEMM for emb + y projection
// ---------------------------------------------------------------------------
__global__ __launch_bounds__(256)
void mgemm_k(const float* __restrict__ A, int M,
             const ushort_t* __restrict__ Bt,
             const float* __restrict__ bias,
             const float* __restrict__ res,
             float* __restrict__ outF, ushort_t* __restrict__ outB,
             int ldo, int epi)
{
    __shared__ ushort_t Al[128][72];
    __shared__ ushort_t Bl[128][72];
    const int tid  = threadIdx.x;
    const int row0 = blockIdx.x * 128;
    const int col0 = blockIdx.y * 128;
    const int wave = tid >> 6, lane = tid & 63;
    const int wr = wave >> 1, wc = wave & 1;
    const int lhi = lane >> 4, llo = lane & 15;

    floatx4 acc[4][4];
    #pragma unroll
    for (int a = 0; a < 4; ++a)
        #pragma unroll
        for (int b = 0; b < 4; ++b)
            #pragma unroll
            for (int q = 0; q < 4; ++q) acc[a][b][q] = 0.f;

    #pragma unroll
    for (int kh = 0; kh < 2; ++kh) {
        const int k0 = kh * 64;
        if (kh) __syncthreads();
        #pragma unroll
        for (int p = 0; p < 8; ++p) {
            int idx = p * 256 + tid;
            int r = idx >> 4, c4 = idx & 15;
            int grow = row0 + r;
            float4 v = make_float4(0.f, 0.f, 0.f, 0.f);
            if (grow < M) v = *(const float4*)(A + (size_t)grow * 128 + k0 + c4 * 4);
            ushort4 pk; pk.x = f2us(v.x); pk.y = f2us(v.y); pk.z = f2us(v.z); pk.w = f2us(v.w);
            *(ushort4*)&Al[r][c4 * 4] = pk;
        }
        #pragma unroll
        for (int p = 0; p < 8; ++p) {
            int idx = p * 256 + tid;
            int n = idx >> 4, c4 = idx & 15;
            ushort4 v = *(const ushort4*)(Bt + (size_t)(col0 + n) * 128 + k0 + c4 * 4);
            *(ushort4*)&Bl[n][c4 * 4] = v;
        }
        __syncthreads();
        #pragma unroll
        for (int ks = 0; ks < 2; ++ks) {
            const int kk = ks * 32 + lhi * 8;
            short8 af[4], bf[4];
            #pragma unroll
            for (int tm = 0; tm < 4; ++tm)
                af[tm] = *(const short8*)&Al[wr * 64 + tm * 16 + llo][kk];
            #pragma unroll
            for (int tn = 0; tn < 4; ++tn)
                bf[tn] = *(const short8*)&Bl[wc * 64 + tn * 16 + llo][kk];
            #pragma unroll
            for (int tm = 0; tm < 4; ++tm)
                #pragma unroll
                for (int tn = 0; tn < 4; ++tn)
                    acc[tm][tn] = __builtin_amdgcn_mfma_f32_16x16x32_bf16(
                        af[tm], bf[tn], acc[tm][tn], 0, 0, 0);
        }
    }

    #pragma unroll
    for (int tm = 0; tm < 4; ++tm) {
        #pragma unroll
        for (int tn = 0; tn < 4; ++tn) {
            int coll = wc * 64 + tn * 16 + llo;
            int gcol = col0 + coll;
            #pragma unroll
            for (int q = 0; q < 4; ++q) {
                int grow = row0 + wr * 64 + tm * 16 + lhi * 4 + q;
                if (grow >= M) continue;
                float t = acc[tm][tn][q];
                if (bias) t += bias[gcol];
                if (epi >= 1) t = siluf(t);
                if (epi == 2) t += res[(size_t)grow * 128 + coll];
                size_t o = (size_t)grow * ldo + gcol;
                if (outB) outB[o] = f2us(t);
                else      outF[o] = t;
            }
        }
    }
}

// ---------------------------------------------------------------------------
// Fused kj/ji: C = silu(x@Wkj+bkj)*rbfp, D = silu(x@Wji+bji)
// ---------------------------------------------------------------------------
__global__ __launch_bounds__(256)
void kjji_k(const float* __restrict__ X,
            const ushort_t* __restrict__ Wkj, const ushort_t* __restrict__ Wji,
            const float* __restrict__ bkj, const float* __restrict__ bji,
            const float* __restrict__ rbf, const float* __restrict__ Wr6,
            float* __restrict__ C, float* __restrict__ D, int M)
{
    __shared__ ushort_t Al[128][136];
    __shared__ ushort_t Bl[128][72];
    __shared__ float Wr[NRR][HD];
    const int tid = threadIdx.x, row0 = blockIdx.x * 128;
    const int wave = tid >> 6, lane = tid & 63;
    const int wr = wave >> 1, wc_ = wave & 1, lhi = lane >> 4, llo = lane & 15;

    #pragma unroll
    for (int p = 0; p < 8; ++p) {
        int idx = p * 256 + tid;
        int r = idx >> 4, c8 = idx & 15;
        int grow = row0 + r;
        float4 v0 = make_float4(0.f,0.f,0.f,0.f), v1 = v0;
        if (grow < M) { const float* s = X + (size_t)grow * HD + c8 * 8;
            v0 = *(const float4*)s; v1 = *(const float4*)(s + 4); }
        ushort8v pk; pk[0]=f2us(v0.x); pk[1]=f2us(v0.y); pk[2]=f2us(v0.z); pk[3]=f2us(v0.w);
        pk[4]=f2us(v1.x); pk[5]=f2us(v1.y); pk[6]=f2us(v1.z); pk[7]=f2us(v1.w);
        *(ushort8v*)&Al[r][c8 * 8] = pk;
    }
    for (int i = tid; i < NRR * HD; i += 256) Wr[i / HD][i & 127] = Wr6[i];

    for (int s = 0; s < 2; ++s) {
        const ushort_t* W = s ? Wji : Wkj;
        floatx4 acc[4][4];
        #pragma unroll
        for (int a = 0; a < 4; ++a)
            #pragma unroll
            for (int b = 0; b < 4; ++b)
                #pragma unroll
                for (int q = 0; q < 4; ++q) acc[a][b][q] = 0.f;
        #pragma unroll
        for (int kh = 0; kh < 2; ++kh) {
            __syncthreads();
            #pragma unroll
            for (int p = 0; p < 4; ++p) {
                int idx = p * 256 + tid;
                int n = idx >> 3, c8 = idx & 7;
                ushort8v v = *(const ushort8v*)(W + (size_t)n * HD + kh * 64 + c8 * 8);
                *(ushort8v*)&Bl[n][c8 * 8] = v;
            }
            __syncthreads();
            #pragma unroll
            for (int ks = 0; ks < 2; ++ks) {
                int kk = ks * 32 + lhi * 8;
                short8 af[4], bf[4];
                #pragma unroll
                for (int tm = 0; tm < 4; ++tm)
                    af[tm] = *(const short8*)&Al[wr * 64 + tm * 16 + llo][kh * 64 + kk];
                #pragma unroll
                for (int tn = 0; tn < 4; ++tn)
                    bf[tn] = *(const short8*)&Bl[wc_ * 64 + tn * 16 + llo][kk];
                #pragma unroll
                for (int tm = 0; tm < 4; ++tm)
                    #pragma unroll
                    for (int tn = 0; tn < 4; ++tn)
                        acc[tm][tn] = __builtin_amdgcn_mfma_f32_16x16x32_bf16(
                            af[tm], bf[tn], acc[tm][tn], 0, 0, 0);
            }
        }
        #pragma unroll
        for (int tm = 0; tm < 4; ++tm)
            #pragma unroll
            for (int tn = 0; tn < 4; ++tn) {
                int coll = wc_ * 64 + tn * 16 + llo;
                #pragma unroll
                for (int q = 0; q < 4; ++q) {
                    int grow = row0 + wr * 64 + tm * 16 + lhi * 4 + q;
                    if (grow >= M) continue;
                    float t = siluf(acc[tm][tn][q] + (s ? bji[coll] : bkj[coll]));
                    if (s == 0) {
                        float rp = 0.f;
                        #pragma unroll
                        for (int r = 0; r < NRR; ++r) rp += rbf[(size_t)grow * NRR + r] * Wr[r][coll];
                        C[(size_t)grow * HD + coll] = t * rp;
                    } else {
                        D[(size_t)grow * HD + coll] = t;
                    }
                }
            }
    }
}

// ---------------------------------------------------------------------------
// Mega chain: bef0,bef1,lin(+x skip),aft0..3 — 7 weights, one kernel.
// Din = h after triplet aggregation (fp32); X = current x (fp32, overwritten).
// ---------------------------------------------------------------------------
__global__ __launch_bounds__(256)
void mega_k(const float* __restrict__ Din, float* X,
            const ushort_t* __restrict__ Wc, const float* __restrict__ Bc, int M)
{
    __shared__ ushort_t Al[128][136];
    __shared__ ushort_t Bl[128][72];
    const int tid = threadIdx.x, row0 = blockIdx.x * 128;
    const int wave = tid >> 6, lane = tid & 63;
    const int wr = wave >> 1, wc_ = wave & 1, lhi = lane >> 4, llo = lane & 15;

    #pragma unroll
    for (int p = 0; p < 8; ++p) {
        int idx = p * 256 + tid;
        int r = idx >> 4, c8 = idx & 15;
        int grow = row0 + r;
        float4 v0 = make_float4(0.f,0.f,0.f,0.f), v1 = v0;
        if (grow < M) { const float* s = Din + (size_t)grow * HD + c8 * 8;
            v0 = *(const float4*)s; v1 = *(const float4*)(s + 4); }
        ushort8v pk; pk[0]=f2us(v0.x); pk[1]=f2us(v0.y); pk[2]=f2us(v0.z); pk[3]=f2us(v0.w);
        pk[4]=f2us(v1.x); pk[5]=f2us(v1.y); pk[6]=f2us(v1.z); pk[7]=f2us(v1.w);
        *(ushort8v*)&Al[r][c8 * 8] = pk;
    }

    for (int s = 0; s < 7; ++s) {
        const ushort_t* W = Wc + (size_t)s * MSZ;
        floatx4 acc[4][4];
        #pragma unroll
        for (int a = 0; a < 4; ++a)
            #pragma unroll
            for (int b = 0; b < 4; ++b)
                #pragma unroll
                for (int q = 0; q < 4; ++q) acc[a][b][q] = 0.f;
        #pragma unroll
        for (int kh = 0; kh < 2; ++kh) {
            __syncthreads();
            #pragma unroll
            for (int p = 0; p < 4; ++p) {
                int idx = p * 256 + tid;
                int n = idx >> 3, c8 = idx & 7;
                ushort8v v = *(const ushort8v*)(W + (size_t)n * HD + kh * 64 + c8 * 8);
                *(ushort8v*)&Bl[n][c8 * 8] = v;
            }
            __syncthreads();
            #pragma unroll
            for (int ks = 0; ks < 2; ++ks) {
                int kk = ks * 32 + lhi * 8;
                short8 af[4], bf[4];
                #pragma unroll
                for (int tm = 0; tm < 4; ++tm)
                    af[tm] = *(const short8*)&Al[wr * 64 + tm * 16 + llo][kh * 64 + kk];
                #pragma unroll
                for (int tn = 0; tn < 4; ++tn)
                    bf[tn] = *(const short8*)&Bl[wc_ * 64 + tn * 16 + llo][kk];
                #pragma unroll
                for (int tm = 0; tm < 4; ++tm)
                    #pragma unroll
                    for (int tn = 0; tn < 4; ++tn)
                        acc[tm][tn] = __builtin_amdgcn_mfma_f32_16x16x32_bf16(
                            af[tm], bf[tn], acc[tm][tn], 0, 0, 0);
            }
        }
        __syncthreads();   // all waves done reading Al before epilogue rewrites it
        #pragma unroll
        for (int tm = 0; tm < 4; ++tm)
            #pragma unroll
            for (int tn = 0; tn < 4; ++tn) {
                int coll = wc_ * 64 + tn * 16 + llo;
                #pragma unroll
                for (int q = 0; q < 4; ++q) {
                    int rowl = wr * 64 + tm * 16 + lhi * 4 + q;
                    int grow = row0 + rowl;
                    bool ok = grow < M;
                    size_t gofs = (size_t)grow * HD + coll;
                    float t = siluf(acc[tm][tn][q] + Bc[s * HD + coll]);
                    float h;
                    if (s == 0 || s == 3 || s == 5) h = t;
                    else if (s == 1) h = t + (ok ? Din[gofs] : 0.f);
                    else { // s == 2, 4, 6: skip stream lives in X
                        float base = ok ? X[gofs] : 0.f;
                        h = t + base;
                        if (ok) X[gofs] = h;
                    }
                    if (s < 6) Al[rowl][coll] = f2us(h);
                }
            }
    }
}

// ---------------------------------------------------------------------------
// Out chain: 3 silu-lins + dot(out_w) + P accumulation, M = NATOMS
// ---------------------------------------------------------------------------
__global__ __launch_bounds__(256)
void outchain_k(const float* __restrict__ T0,
                const ushort_t* __restrict__ Wl, const float* __restrict__ bl,
                const float* __restrict__ wout, float* __restrict__ P, int M)
{
    __shared__ ushort_t Al[128][136];
    __shared__ ushort_t Bl[128][72];
    const int tid = threadIdx.x, row0 = blockIdx.x * 128;
    const int wave = tid >> 6, lane = tid & 63;
    const int wr = wave >> 1, wc_ = wave & 1, lhi = lane >> 4, llo = lane & 15;

    #pragma unroll
    for (int p = 0; p < 8; ++p) {
        int idx = p * 256 + tid;
        int r = idx >> 4, c8 = idx & 15;
        int grow = row0 + r;
        float4 v0 = make_float4(0.f,0.f,0.f,0.f), v1 = v0;
        if (grow < M) { const float* s = T0 + (size_t)grow * HD + c8 * 8;
            v0 = *(const float4*)s; v1 = *(const float4*)(s + 4); }
        ushort8v pk; pk[0]=f2us(v0.x); pk[1]=f2us(v0.y); pk[2]=f2us(v0.z); pk[3]=f2us(v0.w);
        pk[4]=f2us(v1.x); pk[5]=f2us(v1.y); pk[6]=f2us(v1.z); pk[7]=f2us(v1.w);
        *(ushort8v*)&Al[r][c8 * 8] = pk;
    }
    float wv[4];
    #pragma unroll
    for (int tn = 0; tn < 4; ++tn) wv[tn] = wout[wc_ * 64 + tn * 16 + llo];

    for (int s = 0; s < 3; ++s) {
        const ushort_t* W = Wl + (size_t)s * MSZ;
        floatx4 acc[4][4];
        #pragma unroll
        for (int a = 0; a < 4; ++a)
            #pragma unroll
            for (int b = 0; b < 4; ++b)
                #pragma unroll
                for (int q = 0; q < 4; ++q) acc[a][b][q] = 0.f;
        #pragma unroll
        for (int kh = 0; kh < 2; ++kh) {
            __syncthreads();
            #pragma unroll
            for (int p = 0; p < 4; ++p) {
                int idx = p * 256 + tid;
                int n = idx >> 3, c8 = idx & 7;
                ushort8v v = *(const ushort8v*)(W + (size_t)n * HD + kh * 64 + c8 * 8);
                *(ushort8v*)&Bl[n][c8 * 8] = v;
            }
            __syncthreads();
            #pragma unroll
            for (int ks = 0; ks < 2; ++ks) {
                int kk = ks * 32 + lhi * 8;
                short8 af[4], bf[4];
                #pragma unroll
                for (int tm = 0; tm < 4; ++tm)
                    af[tm] = *(const short8*)&Al[wr * 64 + tm * 16 + llo][kh * 64 + kk];
                #pragma unroll
                for (int tn = 0; tn < 4; ++tn)
                    bf[tn] = *(const short8*)&Bl[wc_ * 64 + tn * 16 + llo][kk];
                #pragma unroll
                for (int tm = 0; tm < 4; ++tm)
                    #pragma unroll
                    for (int tn = 0; tn < 4; ++tn)
                        acc[tm][tn] = __builtin_amdgcn_mfma_f32_16x16x32_bf16(
                            af[tm], bf[tn], acc[tm][tn], 0, 0, 0);
            }
        }
        __syncthreads();
        #pragma unroll
        for (int tm = 0; tm < 4; ++tm)
            #pragma unroll
            for (int tn = 0; tn < 4; ++tn) {
                int coll = wc_ * 64 + tn * 16 + llo;
                #pragma unroll
                for (int q = 0; q < 4; ++q)
                    acc[tm][tn][q] = siluf(acc[tm][tn][q] + bl[s * HD + coll]);
            }
        if (s < 2) {
            #pragma unroll
            for (int tm = 0; tm < 4; ++tm)
                #pragma unroll
                for (int tn = 0; tn < 4; ++tn) {
                    int coll = wc_ * 64 + tn * 16 + llo;
                    #pragma unroll
                    for (int q = 0; q < 4; ++q)
                        Al[wr * 64 + tm * 16 + lhi * 4 + q][coll] = f2us(acc[tm][tn][q]);
                }
        } else {
            #pragma unroll
            for (int tm = 0; tm < 4; ++tm)
                #pragma unroll
                for (int q = 0; q < 4; ++q) {
                    float v = 0.f;
                    #pragma unroll
                    for (int tn = 0; tn < 4; ++tn) v += acc[tm][tn][q] * wv[tn];
                    v += __shfl_xor(v, 1); v += __shfl_xor(v, 2);
                    v += __shfl_xor(v, 4); v += __shfl_xor(v, 8);
                    int grow = row0 + wr * 64 + tm * 16 + lhi * 4 + q;
                    if (llo == 0 && grow < M) atomicAdd(&P[grow], v);
                }
        }
    }
}

// ---------------------------------------------------------------------------
// CSR-based gathers (no atomics)
// ---------------------------------------------------------------------------
__global__ __launch_bounds__(256)
void trip_gather_k(const float* __restrict__ sp, const ushort_t* __restrict__ y,
                   const int* __restrict__ toffs, const int* __restrict__ tsorted,
                   const int* __restrict__ idx_kj, float* __restrict__ D,
                   int jbase, int js)
{
    int e = blockIdx.x * 2 + (threadIdx.x >> 7);
    if (e >= NEDGES) return;
    int h = threadIdx.x & 127;
    float acc = 0.f;
    int k1 = toffs[e + 1];
    for (int k = toffs[e]; k < k1; ++k) {
        int t = tsorted[k];
        int ekj = idx_kj[t];
        const float* s = sp + (size_t)t * NBB + jbase;
        const ushort_t* yr = y + (size_t)ekj * (js * HD) + h;
        for (int j = 0; j < js; ++j) acc += s[j] * us2f(yr[j * HD]);
    }
    D[(size_t)e * HD + h] += acc;
}

__global__ __launch_bounds__(256)
void atom_gather_k(const float* __restrict__ X, const float* __restrict__ rbf,
                   const float* __restrict__ Wr6, const int* __restrict__ eoffs,
                   const int* __restrict__ esorted, float* __restrict__ TA)
{
    __shared__ float Wr[NRR][HD];
    int tid = threadIdx.x;
    for (int i = tid; i < NRR * HD; i += 256) Wr[i / HD][i & 127] = Wr6[i];
    __syncthreads();
    int a = blockIdx.x * 2 + (tid >> 7);
    if (a >= NATOMS) return;
    int h = tid & 127;
    float acc = 0.f;
    int k1 = eoffs[a + 1];
    for (int k = eoffs[a]; k < k1; ++k) {
        int e = esorted[k];
        float rp = 0.f;
        #pragma unroll
        for (int r = 0; r < NRR; ++r) rp += rbf[(size_t)e * NRR + r] * Wr[r][h];
        acc += rp * X[(size_t)e * HD + h];
    }
    TA[(size_t)a * HD + h] = acc;
}

// ---------------- small kernels ----------------
__global__ void emb_lin_k(const float* __restrict__ emb_table, const float* __restrict__ emb_w,
                          float* __restrict__ A0, float* __restrict__ A1)
{
    __shared__ float er[HD];
    int a = blockIdx.x, h = threadIdx.x;
    er[h] = emb_table[a * HD + h];
    __syncthreads();
    float acc0 = 0.f, acc1 = 0.f;
    #pragma unroll 8
    for (int l = 0; l < HD; ++l) {
        float e = er[l];
        acc0 += e * emb_w[l * HD + h];
        acc1 += e * emb_w[(HD + l) * HD + h];
    }
    A0[a * HD + h] = acc0;
    A1[a * HD + h] = acc1;
}

__global__ void rbfh_k(const float* __restrict__ rbf, const float* __restrict__ W,
                       const float* __restrict__ bb, float* __restrict__ out)
{
    int idx = blockIdx.x * 256 + threadIdx.x;
    if (idx >= NEDGES * HD) return;
    int e = idx >> 7, h = idx & 127;
    float acc = bb[h];
    #pragma unroll
    for (int r = 0; r < NRR; ++r) acc += rbf[e * NRR + r] * W[r * HD + h];
    out[idx] = siluf(acc);
}

__global__ void emb_fin_k(const float* __restrict__ lin3, const int* __restrict__ z,
                          const int* __restrict__ ii, const int* __restrict__ jj,
                          const float* __restrict__ A0, const float* __restrict__ A1,
                          const float* __restrict__ emb_b, float* __restrict__ x)
{
    int idx = blockIdx.x * 256 + threadIdx.x;
    if (idx >= NEDGES * HD) return;
    int e = idx >> 7, h = idx & 127;
    int zi = z[ii[e]], zj = z[jj[e]];
    float t = lin3[idx] + A0[zi * HD + h] + A1[zj * HD + h] + emb_b[h];
    x[idx] = siluf(t);
}

__global__ void sbf_proj_k(const float* __restrict__ sbf, const float* __restrict__ W,
                           float* __restrict__ sp)
{
    __shared__ float Ws[NSNR * NBB];
    for (int s = threadIdx.x; s < NSNR * NBB; s += 256) Ws[s] = W[s];
    __syncthreads();
    int t = blockIdx.x * 256 + threadIdx.x;
    if (t >= NTRIP) return;
    float acc[NBB];
    #pragma unroll
    for (int n = 0; n < NBB; ++n) acc[n] = 0.f;
    #pragma unroll
    for (int r = 0; r < NSNR; ++r) {
        float v = sbf[(size_t)t * NSNR + r];
        #pragma unroll
        for (int n = 0; n < NBB; ++n) acc[n] += v * Ws[r * NBB + n];
    }
    #pragma unroll
    for (int n = 0; n < NBB; ++n) sp[(size_t)t * NBB + n] = acc[n];
}

__global__ void graph_sum_k(const float* __restrict__ P, const int* __restrict__ batch,
                            float* __restrict__ outg)
{
    int a = blockIdx.x * 256 + threadIdx.x;
    if (a >= NATOMS) return;
    atomicAdd(&outg[batch[a]], P[a]);
}

// ---------------------------------------------------------------------------
extern "C" void kernel_launch(void* const* d_in, const int* in_sizes, int n_in,
                              void* d_out, int out_size, void* d_ws, size_t ws_size,
                              hipStream_t stream)
{
    const int*   z         = (const int*)  d_in[0];
    const float* rbf       = (const float*)d_in[1];
    const float* sbf       = (const float*)d_in[2];
    const int*   ii        = (const int*)  d_in[3];
    const int*   jj        = (const int*)  d_in[4];
    const int*   idx_kj    = (const int*)  d_in[5];
    const int*   idx_ji    = (const int*)  d_in[6];
    const int*   batch     = (const int*)  d_in[7];
    const float* emb_table = (const float*)d_in[8];
    const float* emb_rbf_w = (const float*)d_in[9];
    const float* emb_rbf_b = (const float*)d_in[10];
    const float* emb_w     = (const float*)d_in[11];
    const float* emb_b     = (const float*)d_in[12];
    const float* int_rbf_w = (const float*)d_in[13];
    const float* int_sbf_w = (const float*)d_in[14];
    const float* int_kj_w  = (const float*)d_in[15];
    const float* int_kj_b  = (const float*)d_in[16];
    const float* int_ji_w  = (const float*)d_in[17];
    const float* int_ji_b  = (const float*)d_in[18];
    const float* int_W     = (const float*)d_in[19];
    const float* int_bef_w = (const float*)d_in[20];
    const float* int_bef_b = (const float*)d_in[21];
    const float* int_lin_w = (const float*)d_in[22];
    const float* int_lin_b = (const float*)d_in[23];
    const float* int_aft_w = (const float*)d_in[24];
    const float* int_aft_b = (const float*)d_in[25];
    const float* out_rbf_w = (const float*)d_in[26];
    const float* out_lins_w= (const float*)d_in[27];
    const float* out_lins_b= (const float*)d_in[28];
    const float* out_w     = (const float*)d_in[29];
    float* d_outf          = (float*)d_out;

    const size_t EH = (size_t)NEDGES * HD;
    const int OFF_EMB = 0, OFF_KJ = 1, OFF_JI = 7, OFF_CHAIN = 13, OFF_OUTL = 55;

    // ---- workspace layout ----
    char* base = (char*)d_ws;
    auto take = [&](size_t bytes) { char* p = base; base += (bytes + 255) & ~(size_t)255; return p; };
    float* bufA    = (float*)take(EH * 4);
    float* bufC    = (float*)take(EH * 4);
    float* bufD    = (float*)take(EH * 4);
    float* sbfp    = (float*)take((size_t)NTRIP * NBB * 4);
    float* t_atom  = (float*)take((size_t)NATOMS * HD * 4);
    float* P_atom  = (float*)take((size_t)NATOMS * 4);
    float* A0      = (float*)take(95 * HD * 4);
    float* A1      = (float*)take(95 * HD * 4);
    float* bc      = (float*)take((size_t)NBLKS * 7 * HD * 4);
    int*   counts  = (int*)  take((size_t)(NEDGES + 1) * 4);
    int*   bsum    = (int*)  take(1024 * 4);
    int*   toffs   = (int*)  take((size_t)(NEDGES + 1) * 4);
    int*   eoffs   = (int*)  take((size_t)(NATOMS + 1) * 4);
    int*   tsorted = (int*)  take((size_t)NTRIP * 4);
    int*   esorted = (int*)  take((size_t)NEDGES * 4);
    ushort_t* w128 = (ushort_t*)take((size_t)76 * MSZ * 2);
    ushort_t* wY   = (ushort_t*)take((size_t)NBLKS * 1024 * 128 * 2);
    size_t fixed = (size_t)(base - (char*)d_ws);
    ushort_t* ybuf = (ushort_t*)base;

    int nsplit = 8;
    for (int s = 1; s <= 8; s *= 2) {
        size_t yb = (size_t)NEDGES * (NBB / s) * HD * 2;
        if (fixed + yb <= ws_size) { nsplit = s; break; }
    }
    const int JS = NBB / nsplit;

    auto zero = [&](float* p, size_t n) {
        zerof_k<<<((int)n + 255) / 256, 256, 0, stream>>>(p, (int)n);
    };

    // ---------------- weight prep ----------------
    transp128_k<<< 1, 256, 0, stream>>>(emb_w + 2 * MSZ, w128 + (size_t)OFF_EMB * MSZ);
    transp128_k<<< 6, 256, 0, stream>>>(int_kj_w,   w128 + (size_t)OFF_KJ  * MSZ);
    transp128_k<<< 6, 256, 0, stream>>>(int_ji_w,   w128 + (size_t)OFF_JI  * MSZ);
    for (int b = 0; b < NBLKS; ++b) {
        transp128_k<<<2, 256, 0, stream>>>(int_bef_w + (size_t)b * 2 * MSZ,
                                           w128 + (size_t)(OFF_CHAIN + b * 7) * MSZ);
        transp128_k<<<1, 256, 0, stream>>>(int_lin_w + (size_t)b * MSZ,
                                           w128 + (size_t)(OFF_CHAIN + b * 7 + 2) * MSZ);
        transp128_k<<<4, 256, 0, stream>>>(int_aft_w + (size_t)b * 4 * MSZ,
                                           w128 + (size_t)(OFF_CHAIN + b * 7 + 3) * MSZ);
    }
    transp128_k<<<21, 256, 0, stream>>>(out_lins_w, w128 + (size_t)OFF_OUTL * MSZ);
    transpWY_k<<<(NBLKS * 1024 + 255) / 256, 256, 0, stream>>>(int_W, wY);
    pack_bc_k<<<NBLKS, 256, 0, stream>>>(int_bef_b, int_lin_b, int_aft_b, bc);

    // ---------------- CSR builds ----------------
    {   // triplet -> edge (idx_ji)
        zeroi_k<<<(NEDGES + 255) / 256, 256, 0, stream>>>(counts, NEDGES);
        hist_k<<<(NTRIP + 255) / 256, 256, 0, stream>>>(idx_ji, NTRIP, counts);
        int nb = (NEDGES + 255) / 256;
        blksum_k<<<nb, 256, 0, stream>>>(counts, NEDGES, bsum);
        scanb_k<<<1, 1024, 0, stream>>>(bsum, nb);
        scanfin_k<<<nb, 256, 0, stream>>>(counts, NEDGES, bsum, toffs);
        zeroi_k<<<(NEDGES + 255) / 256, 256, 0, stream>>>(counts, NEDGES);
        fill_k<<<(NTRIP + 255) / 256, 256, 0, stream>>>(idx_ji, NTRIP, toffs, counts, tsorted);
    }
    {   // edge -> atom (i)
        zeroi_k<<<(NATOMS + 255) / 256, 256, 0, stream>>>(counts, NATOMS);
        hist_k<<<(NEDGES + 255) / 256, 256, 0, stream>>>(ii, NEDGES, counts);
        int nb = (NATOMS + 255) / 256;
        blksum_k<<<nb, 256, 0, stream>>>(counts, NATOMS, bsum);
        scanb_k<<<1, 1024, 0, stream>>>(bsum, nb);
        scanfin_k<<<nb, 256, 0, stream>>>(counts, NATOMS, bsum, eoffs);
        zeroi_k<<<(NATOMS + 255) / 256, 256, 0, stream>>>(counts, NATOMS);
        fill_k<<<(NEDGES + 255) / 256, 256, 0, stream>>>(ii, NEDGES, eoffs, counts, esorted);
    }

    const int EGRID = (NEDGES + 127) / 128;
    auto out_block = [&](const float* xe, int k) {
        atom_gather_k<<<(NATOMS + 1) / 2, 256, 0, stream>>>(
            xe, rbf, out_rbf_w + (size_t)k * NRR * HD, eoffs, esorted, t_atom);
        outchain_k<<<(NATOMS + 127) / 128, 256, 0, stream>>>(
            t_atom, w128 + (size_t)(OFF_OUTL + 3 * k) * MSZ,
            out_lins_b + (size_t)k * 3 * HD, out_w + (size_t)k * HD, P_atom, NATOMS);
    };

    // ---------------- Embedding block ----------------
    emb_lin_k<<<95, HD, 0, stream>>>(emb_table, emb_w, A0, A1);
    rbfh_k<<<(NEDGES * HD + 255) / 256, 256, 0, stream>>>(rbf, emb_rbf_w, emb_rbf_b, bufC);
    mgemm_k<<<dim3(EGRID, 1), 256, 0, stream>>>(bufC, NEDGES, w128 + (size_t)OFF_EMB * MSZ,
                                                nullptr, nullptr, bufD, nullptr, HD, 0);
    emb_fin_k<<<(NEDGES * HD + 255) / 256, 256, 0, stream>>>(bufD, z, ii, jj, A0, A1, emb_b, bufA);

    zero(P_atom, NATOMS);
    out_block(bufA, 0);

    // ---------------- Interaction blocks ----------------
    for (int b = 0; b < NBLKS; ++b) {
        sbf_proj_k<<<(NTRIP + 255) / 256, 256, 0, stream>>>(
            sbf, int_sbf_w + (size_t)b * NSNR * NBB, sbfp);

        kjji_k<<<EGRID, 256, 0, stream>>>(
            bufA,
            w128 + (size_t)(OFF_KJ + b) * MSZ, w128 + (size_t)(OFF_JI + b) * MSZ,
            int_kj_b + (size_t)b * HD, int_ji_b + (size_t)b * HD,
            rbf, int_rbf_w + (size_t)b * NRR * HD,
            bufC, bufD, NEDGES);

        for (int p = 0; p < nsplit; ++p) {
            mgemm_k<<<dim3(EGRID, JS), 256, 0, stream>>>(
                bufC, NEDGES, wY + ((size_t)b * 1024 + (size_t)p * JS * 128) * 128,
                nullptr, nullptr, nullptr, ybuf, JS * HD, 0);
            trip_gather_k<<<(NEDGES + 1) / 2, 256, 0, stream>>>(
                sbfp, ybuf, toffs, tsorted, idx_kj, bufD, p * JS, JS);
        }

        mega_k<<<EGRID, 256, 0, stream>>>(
            bufD, bufA, w128 + (size_t)(OFF_CHAIN + b * 7) * MSZ,
            bc + (size_t)b * 7 * HD, NEDGES);

        out_block(bufA, b + 1);
    }

    // ---------------- Final graph reduction ----------------
    zero(d_outf, NGRAPH);
    graph_sum_k<<<(NATOMS + 255) / 256, 256, 0, stream>>>(P_atom, batch, d_outf);
}